// Round 1
// baseline (9.697 us; speedup 1.0000x reference)
//
#include <hip/hip_runtime.h>

// SoftmaxEncoder_20160576488053
//
// Key insight: the reference's cot/transformer loop only APPENDS rows to H
// (H = concat([H_input, H_cot])); rows 0..287 are the initial embedding and
// are never modified. The readout uses H[:, :11, :] only, so the entire
// transformer stack is dead code with respect to the output.
//
//   zs row p (p<11 => p<256):  [ ys[b,p,0:32] | (p<5 ? xs[b,p,0:32] : 0) | 0... ]
//   H0[b,p,:] = zs[b,p,:] @ read_in_w + read_in_b      (only first 64 cols of zs nonzero)
//   out[b,p,c'] = H0[b,p,:] @ read_out_w[:, 32+c'] + read_out_b[32+c'],  c' in [0,96)
//
// Input order: 0 xs, 1 ys, 2 head_mask, 3 read_in_w, 4 read_in_b, 5 wq, 6 wk,
// 7 wv, 8 ln1_g, 9 ln1_b, 10 mlp_w1, 11 mlp_b1, 12 mlp_w2, 13 mlp_b2,
// 14 read_out_w, 15 read_out_b. Output: (64, 11, 96) float32.

#define BB     64
#define NPT    11
#define DD     32
#define EE     128
#define HALFN  5

__global__ __launch_bounds__(128) void readout_kernel(
    const float* __restrict__ xs,    // (64, 256, 32)
    const float* __restrict__ ys,    // (64, 256, 32)
    const float* __restrict__ w_in,  // (128, 128) row-major
    const float* __restrict__ b_in,  // (128)
    const float* __restrict__ w_out, // (128, 128) row-major
    const float* __restrict__ b_out, // (128)
    float* __restrict__ out)         // (64, 11, 96)
{
    const int b = blockIdx.x / NPT;
    const int p = blockIdx.x % NPT;
    const int t = threadIdx.x;

    __shared__ float zrow[2 * DD];   // 64 nonzero embedding inputs
    __shared__ float hrow[EE];       // H0 row

    if (t < DD) {
        zrow[t] = ys[(b * 256 + p) * DD + t];
    } else if (t < 2 * DD) {
        zrow[t] = (p < HALFN) ? xs[(b * 256 + p) * DD + (t - DD)] : 0.0f;
    }
    __syncthreads();

    // H0[b,p,t] = b_in[t] + sum_{e<64} zrow[e] * w_in[e, t]
    float h = b_in[t];
    #pragma unroll 8
    for (int e = 0; e < 2 * DD; ++e) {
        h = fmaf(zrow[e], w_in[e * EE + t], h);   // coalesced across t
    }
    hrow[t] = h;
    __syncthreads();

    // out[b,p,t] = b_out[32+t] + sum_f hrow[f] * w_out[f, 32+t]   (t < 96)
    if (t < 96) {
        float o = b_out[DD + t];
        #pragma unroll 8
        for (int f = 0; f < EE; ++f) {
            o = fmaf(hrow[f], w_out[f * EE + DD + t], o);  // coalesced across t
        }
        out[(b * NPT + p) * 96 + t] = o;
    }
}

extern "C" void kernel_launch(void* const* d_in, const int* in_sizes, int n_in,
                              void* d_out, int out_size, void* d_ws, size_t ws_size,
                              hipStream_t stream) {
    const float* xs    = (const float*)d_in[0];
    const float* ys    = (const float*)d_in[1];
    const float* w_in  = (const float*)d_in[3];
    const float* b_in  = (const float*)d_in[4];
    const float* w_out = (const float*)d_in[14];
    const float* b_out = (const float*)d_in[15];
    float* out = (float*)d_out;

    readout_kernel<<<BB * NPT, 128, 0, stream>>>(xs, ys, w_in, b_in, w_out, b_out, out);
}